// Round 13
// baseline (41.800 us; speedup 1.0000x reference)
//
#include <hip/hip_runtime.h>
#include <hip/hip_bf16.h>

// Problem constants
#define B_ 4
#define S_ 4096
#define H_ 1024
#define D_ 64
#define BK 64
#define KSTEPS (H_ / BK)   // 16

typedef short bf16x8 __attribute__((ext_vector_type(8)));
typedef float f32x4 __attribute__((ext_vector_type(4)));

__device__ inline unsigned short f2bf(float f) {
    union { float f; unsigned u; } v; v.f = f;
    return (unsigned short)((v.u + 0x7fffu + ((v.u >> 16) & 1u)) >> 16);
}
__device__ inline bf16x8 cvt8v(f32x4 a, f32x4 b) {
    bf16x8 r;
    r[0] = (short)f2bf(a[0]); r[1] = (short)f2bf(a[1]);
    r[2] = (short)f2bf(a[2]); r[3] = (short)f2bf(a[3]);
    r[4] = (short)f2bf(b[0]); r[5] = (short)f2bf(b[1]);
    r[6] = (short)f2bf(b[2]); r[7] = (short)f2bf(b[3]);
    return r;
}

// ---------- prep_w3z (round-12 proven): weight transpose + M8acc zeroing ----------
__global__ void prep_w3z(const float* __restrict__ Wk, const float* __restrict__ Wv,
                         const float* __restrict__ Wq, unsigned short* __restrict__ WT,
                         float* __restrict__ M8acc) {
    int gid = blockIdx.x * 256 + threadIdx.x;  // pj*65536 + d*1024 + h
    if (gid < 16384) M8acc[gid] = 0.f;
    int pj = gid >> 16;
    int d = (gid >> 10) & 63;
    int h = gid & 1023;
    const float* W = (pj == 0) ? Wk : (pj == 1) ? Wv : Wq;
    WT[gid] = f2bf(W[h * D_ + d]);
}

// ---------- kv_moment14: round-12 structure; sc0 (L1-bypass, L2-served) loads ----------
// LDS (ushort idx): x bufs L[0..4095],[4096..8191]; W[pj][buf] at 8192+(pj*2+buf)*4096.
// Tiles [64 rows][8 slots x 8 bf16], slot swizzle sf = slot ^ (row&7)  (proven).
__global__ __launch_bounds__(768)
void kv_moment14(const float* __restrict__ x, const unsigned short* __restrict__ WT,
                 float* __restrict__ M8acc, unsigned short* __restrict__ Qb) {
    int blk = blockIdx.x;            // 0..255
    int b = blk >> 6;
    int s0 = (blk & 63) * 64;
    int tid = threadIdx.x;
    int w = tid >> 6, lane = tid & 63;
    int r = lane & 15, kg = lane >> 4;
    int sv = w & 3, pj = w >> 2;     // s-subtile 0..3; 0=K 1=V 2=Q

    __shared__ __align__(16) unsigned short L[32768];  // 64 KB

    // x staging map (threads 0..511, round-8 proven)
    int strow = tid >> 3, sts = tid & 7;
    int sf_st = sts ^ (strow & 7);
    // weight staging map: 1536 slots of 16B, 2 per thread (round-9 proven)
    int ws0 = tid * 2, ws1 = tid * 2 + 1;
    int wpj0 = ws0 >> 9, wpj1 = ws1 >> 9;
    int wp0 = ws0 & 511, wp1 = ws1 & 511;
    int wrow0 = wp0 >> 3, wst0 = wp0 & 7, wsf0 = wst0 ^ (wrow0 & 7);
    int wrow1 = wp1 >> 3, wst1 = wp1 & 7, wsf1 = wst1 ^ (wrow1 & 7);

    const float* xbase = x + ((size_t)b * S_ + s0) * H_;

    f32x4 xr0, xr1;
    bf16x8 wr0, wr1;

    // volatile vector loads -> global_load_dwordx4 ... sc0 (no L1 allocation; L2-served)
#define LOADX(KS) do { if (tid < 512) {                                       \
        const float* src = xbase + (size_t)strow * H_ + (KS) * BK + sts * 8;  \
        xr0 = *(const volatile f32x4*)(src);                                  \
        xr1 = *(const volatile f32x4*)(src + 4); } } while (0)
#define LOADW(KS) do {                                                        \
        wr0 = *(const volatile bf16x8*)(WT + wpj0 * 65536 + wrow0 * H_ + (KS) * BK + wst0 * 8); \
        wr1 = *(const volatile bf16x8*)(WT + wpj1 * 65536 + wrow1 * H_ + (KS) * BK + wst1 * 8); \
    } while (0)
#define WRITE(BUF) do {                                                       \
        if (tid < 512)                                                        \
            *(bf16x8*)&L[(BUF) * 4096 + strow * 64 + sf_st * 8] = cvt8v(xr0, xr1); \
        *(bf16x8*)&L[8192 + (wpj0 * 2 + (BUF)) * 4096 + wrow0 * 64 + wsf0 * 8] = wr0; \
        *(bf16x8*)&L[8192 + (wpj1 * 2 + (BUF)) * 4096 + wrow1 * 64 + wsf1 * 8] = wr1; \
    } while (0)

    LOADX(0); LOADW(0);
    WRITE(0);
    LOADX(1); LOADW(1);
    __syncthreads();

    f32x4 acc[4] = {};
    int arow_off = (sv * 16 + r) * 64;

    for (int ks = 0; ks < KSTEPS; ++ks) {
        int cur = ks & 1;
        if (ks < KSTEPS - 1) WRITE(cur ^ 1);
        if (ks < KSTEPS - 2) { LOADX(ks + 2); LOADW(ks + 2); }
#pragma unroll
        for (int kc = 0; kc < 2; ++kc) {
            int slot = kc * 4 + kg;
            int sf = (slot ^ (r & 7)) * 8;
            bf16x8 af = *(const bf16x8*)&L[cur * 4096 + arow_off + sf];
#pragma unroll
            for (int nt = 0; nt < 4; ++nt) {
                bf16x8 bw = *(const bf16x8*)&L[8192 + (pj * 2 + cur) * 4096 + (nt * 16 + r) * 64 + sf];
                acc[nt] = __builtin_amdgcn_mfma_f32_16x16x32_bf16(af, bw, acc[nt], 0, 0, 0);
            }
        }
        __syncthreads();
    }

    // K,V -> LDS (proven D-layout); Q -> global Qb
    if (pj < 2) {
#pragma unroll
        for (int nt = 0; nt < 4; ++nt)
#pragma unroll
            for (int i = 0; i < 4; ++i)
                L[pj * 4096 + (sv * 16 + kg * 4 + i) * 64 + nt * 16 + r] = f2bf(acc[nt][i]);
    }
    __syncthreads();
    if (pj == 2) {
        unsigned short* qrow = Qb + ((size_t)b * S_ + s0 + sv * 16) * 64;
#pragma unroll
        for (int nt = 0; nt < 4; ++nt)
#pragma unroll
            for (int i = 0; i < 4; ++i)
                qrow[(kg * 4 + i) * 64 + nt * 16 + r] = f2bf(acc[nt][i]);
    } else if (w < 8) {
        // Stage 2 (proven math): Mpart[e][d] = sum_{s<64} K[s][e]*V[s][d]
        int et = w & 3, dh2 = w >> 2;
        f32x4 accM[2] = {};
#pragma unroll
        for (int ks2 = 0; ks2 < 2; ++ks2) {
            bf16x8 afm;
#pragma unroll
            for (int i = 0; i < 8; ++i)
                afm[i] = (short)L[(ks2 * 32 + kg * 8 + i) * 64 + et * 16 + r];
#pragma unroll
            for (int t = 0; t < 2; ++t) {
                int nt = dh2 * 2 + t;
                bf16x8 bfv;
#pragma unroll
                for (int i = 0; i < 8; ++i)
                    bfv[i] = (short)L[4096 + (ks2 * 32 + kg * 8 + i) * 64 + nt * 16 + r];
                accM[t] = __builtin_amdgcn_mfma_f32_16x16x32_bf16(afm, bfv, accM[t], 0, 0, 0);
            }
        }
        // fp32 accumulate into device-wide M (zeroed by prep_w3z; device-scope atomics)
        float* Mb = M8acc + b * 4096;
#pragma unroll
        for (int t = 0; t < 2; ++t)
#pragma unroll
            for (int i = 0; i < 4; ++i) {
                int idx = (et * 16 + kg * 4 + i) * 64 + (dh2 * 2 + t) * 16 + r;
                atomicAdd(&Mb[idx], accM[t][i]);
            }
    }
#undef LOADX
#undef LOADW
#undef WRITE
}

// ---------- final_qm (round-12 proven): out = Q @ (M/8) ----------
__global__ __launch_bounds__(256)
void final_qm(const unsigned short* __restrict__ Qb, const float* __restrict__ M8acc,
              float* __restrict__ out) {
    int blk = blockIdx.x;            // 0..255
    int b = blk >> 6;
    int s0 = (blk & 63) * 64;
    int tid = threadIdx.x;
    int wv = tid >> 6, lane = tid & 63;
    int r = lane & 15, kg = lane >> 4;

    __shared__ unsigned short Ml[4096];  // M/8 as bf16 [e][d]
#pragma unroll
    for (int j = 0; j < 16; ++j) {
        int i2 = j * 256 + tid;
        Ml[i2] = f2bf(M8acc[b * 4096 + i2] * 0.125f);
    }
    __syncthreads();

    const unsigned short* qrow = Qb + ((size_t)b * S_ + s0 + wv * 16 + r) * 64;
    f32x4 acc[4] = {};
#pragma unroll
    for (int ks2 = 0; ks2 < 2; ++ks2) {
        bf16x8 af = *(const bf16x8*)(qrow + ks2 * 32 + kg * 8);
#pragma unroll
        for (int nt = 0; nt < 4; ++nt) {
            bf16x8 bfm;
#pragma unroll
            for (int i = 0; i < 8; ++i)
                bfm[i] = (short)Ml[(ks2 * 32 + kg * 8 + i) * 64 + nt * 16 + r];
            acc[nt] = __builtin_amdgcn_mfma_f32_16x16x32_bf16(af, bfm, acc[nt], 0, 0, 0);
        }
    }
    float* orow = out + ((size_t)b * S_ + s0 + wv * 16) * 64;
#pragma unroll
    for (int nt = 0; nt < 4; ++nt)
#pragma unroll
        for (int i = 0; i < 4; ++i)
            orow[(kg * 4 + i) * 64 + nt * 16 + r] = acc[nt][i];
}

extern "C" void kernel_launch(void* const* d_in, const int* in_sizes, int n_in,
                              void* d_out, int out_size, void* d_ws, size_t ws_size,
                              hipStream_t stream) {
    const float* x  = (const float*)d_in[0];
    const float* Wk = (const float*)d_in[1];
    const float* Wq = (const float*)d_in[2];
    const float* Wv = (const float*)d_in[3];
    float* out = (float*)d_out;

    if (ws_size < 2555904) return;  // diagnostic guard

    char* ws = (char*)d_ws;
    // layout (total 2,555,904 B):
    // WT[384K bf16 x3] | M8acc[64K fp32] | Qb[2M bf16]
    unsigned short* WT  = (unsigned short*)(ws);
    float* M8acc        = (float*)(ws + 393216);
    unsigned short* Qb  = (unsigned short*)(ws + 458752);

    prep_w3z<<<768, 256, 0, stream>>>(Wk, Wv, Wq, WT, M8acc);
    kv_moment14<<<256, 768, 0, stream>>>(x, WT, M8acc, Qb);
    final_qm<<<256, 256, 0, stream>>>(Qb, M8acc, out);
}

// Round 14
// 30.036 us; speedup vs baseline: 1.3917x; 1.3917x over previous
//
#include <hip/hip_runtime.h>
#include <hip/hip_bf16.h>

// Problem constants
#define B_ 4
#define S_ 4096
#define H_ 1024
#define D_ 64
#define BK 64
#define KSTEPS (H_ / BK)   // 16

typedef short bf16x8 __attribute__((ext_vector_type(8)));
typedef float f32x4 __attribute__((ext_vector_type(4)));

__device__ inline unsigned short f2bf(float f) {
    union { float f; unsigned u; } v; v.f = f;
    return (unsigned short)((v.u + 0x7fffu + ((v.u >> 16) & 1u)) >> 16);
}
__device__ inline bf16x8 cvt8(const float4& a, const float4& b) {
    bf16x8 r;
    r[0] = (short)f2bf(a.x); r[1] = (short)f2bf(a.y);
    r[2] = (short)f2bf(a.z); r[3] = (short)f2bf(a.w);
    r[4] = (short)f2bf(b.x); r[5] = (short)f2bf(b.y);
    r[6] = (short)f2bf(b.z); r[7] = (short)f2bf(b.w);
    return r;
}

// ---------- prep_w3z: weight transpose (round-9 proven) + M8acc zeroing ----------
__global__ void prep_w3z(const float* __restrict__ Wk, const float* __restrict__ Wv,
                         const float* __restrict__ Wq, unsigned short* __restrict__ WT,
                         float* __restrict__ M8acc) {
    int gid = blockIdx.x * 256 + threadIdx.x;  // pj*65536 + d*1024 + h
    if (gid < 16384) M8acc[gid] = 0.f;
    int pj = gid >> 16;
    int d = (gid >> 10) & 63;
    int h = gid & 1023;
    const float* W = (pj == 0) ? Wk : (pj == 1) ? Wv : Wq;
    WT[gid] = f2bf(W[h * D_ + d]);
}

// ---------- kv_moment13: round-9 proven structure; stage-2 -> fp32 atomicAdd ----------
// LDS (ushort idx): x bufs L[0..4095],[4096..8191]; W[pj][buf] at 8192+(pj*2+buf)*4096.
// Tiles [64 rows][8 slots x 8 bf16], slot swizzle sf = slot ^ (row&7)  (proven).
__global__ __launch_bounds__(768)
void kv_moment13(const float* __restrict__ x, const unsigned short* __restrict__ WT,
                 float* __restrict__ M8acc, unsigned short* __restrict__ Qb) {
    int blk = blockIdx.x;            // 0..255
    int b = blk >> 6;
    int s0 = (blk & 63) * 64;
    int tid = threadIdx.x;
    int w = tid >> 6, lane = tid & 63;
    int r = lane & 15, kg = lane >> 4;
    int sv = w & 3, pj = w >> 2;     // s-subtile 0..3; 0=K 1=V 2=Q

    __shared__ __align__(16) unsigned short L[32768];  // 64 KB

    // x staging map (threads 0..511, round-8 proven)
    int strow = tid >> 3, sts = tid & 7;
    int sf_st = sts ^ (strow & 7);
    // weight staging map: 1536 slots of 16B, 2 per thread (round-9 proven)
    int ws0 = tid * 2, ws1 = tid * 2 + 1;
    int wpj0 = ws0 >> 9, wpj1 = ws1 >> 9;
    int wp0 = ws0 & 511, wp1 = ws1 & 511;
    int wrow0 = wp0 >> 3, wst0 = wp0 & 7, wsf0 = wst0 ^ (wrow0 & 7);
    int wrow1 = wp1 >> 3, wst1 = wp1 & 7, wsf1 = wst1 ^ (wrow1 & 7);

    const float* xbase = x + ((size_t)b * S_ + s0) * H_;

    float4 xr0, xr1;
    bf16x8 wr0, wr1;

#define LOADX(KS) do { if (tid < 512) {                                       \
        const float* src = xbase + (size_t)strow * H_ + (KS) * BK + sts * 8;  \
        xr0 = *(const float4*)(src);                                          \
        xr1 = *(const float4*)(src + 4); } } while (0)
#define LOADW(KS) do {                                                        \
        wr0 = *(const bf16x8*)(WT + wpj0 * 65536 + wrow0 * H_ + (KS) * BK + wst0 * 8); \
        wr1 = *(const bf16x8*)(WT + wpj1 * 65536 + wrow1 * H_ + (KS) * BK + wst1 * 8); \
    } while (0)
#define WRITE(BUF) do {                                                       \
        if (tid < 512)                                                        \
            *(bf16x8*)&L[(BUF) * 4096 + strow * 64 + sf_st * 8] = cvt8(xr0, xr1); \
        *(bf16x8*)&L[8192 + (wpj0 * 2 + (BUF)) * 4096 + wrow0 * 64 + wsf0 * 8] = wr0; \
        *(bf16x8*)&L[8192 + (wpj1 * 2 + (BUF)) * 4096 + wrow1 * 64 + wsf1 * 8] = wr1; \
    } while (0)

    LOADX(0); LOADW(0);
    WRITE(0);
    LOADX(1); LOADW(1);
    __syncthreads();

    f32x4 acc[4] = {};
    int arow_off = (sv * 16 + r) * 64;

    for (int ks = 0; ks < KSTEPS; ++ks) {
        int cur = ks & 1;
        if (ks < KSTEPS - 1) WRITE(cur ^ 1);
        if (ks < KSTEPS - 2) { LOADX(ks + 2); LOADW(ks + 2); }
#pragma unroll
        for (int kc = 0; kc < 2; ++kc) {
            int slot = kc * 4 + kg;
            int sf = (slot ^ (r & 7)) * 8;
            bf16x8 af = *(const bf16x8*)&L[cur * 4096 + arow_off + sf];
#pragma unroll
            for (int nt = 0; nt < 4; ++nt) {
                bf16x8 bw = *(const bf16x8*)&L[8192 + (pj * 2 + cur) * 4096 + (nt * 16 + r) * 64 + sf];
                acc[nt] = __builtin_amdgcn_mfma_f32_16x16x32_bf16(af, bw, acc[nt], 0, 0, 0);
            }
        }
        __syncthreads();
    }

    // K,V -> LDS (proven D-layout); Q -> global Qb
    if (pj < 2) {
#pragma unroll
        for (int nt = 0; nt < 4; ++nt)
#pragma unroll
            for (int i = 0; i < 4; ++i)
                L[pj * 4096 + (sv * 16 + kg * 4 + i) * 64 + nt * 16 + r] = f2bf(acc[nt][i]);
    }
    __syncthreads();
    if (pj == 2) {
        unsigned short* qrow = Qb + ((size_t)b * S_ + s0 + sv * 16) * 64;
#pragma unroll
        for (int nt = 0; nt < 4; ++nt)
#pragma unroll
            for (int i = 0; i < 4; ++i)
                qrow[(kg * 4 + i) * 64 + nt * 16 + r] = f2bf(acc[nt][i]);
    } else if (w < 8) {
        // Stage 2 (proven math): Mpart[e][d] = sum_{s<64} K[s][e]*V[s][d]
        int et = w & 3, dh2 = w >> 2;
        f32x4 accM[2] = {};
#pragma unroll
        for (int ks2 = 0; ks2 < 2; ++ks2) {
            bf16x8 afm;
#pragma unroll
            for (int i = 0; i < 8; ++i)
                afm[i] = (short)L[(ks2 * 32 + kg * 8 + i) * 64 + et * 16 + r];
#pragma unroll
            for (int t = 0; t < 2; ++t) {
                int nt = dh2 * 2 + t;
                bf16x8 bfv;
#pragma unroll
                for (int i = 0; i < 8; ++i)
                    bfv[i] = (short)L[4096 + (ks2 * 32 + kg * 8 + i) * 64 + nt * 16 + r];
                accM[t] = __builtin_amdgcn_mfma_f32_16x16x32_bf16(afm, bfv, accM[t], 0, 0, 0);
            }
        }
        // fp32 accumulate into device-wide M (zeroed by prep_w3z; device-scope atomics)
        float* Mb = M8acc + b * 4096;
#pragma unroll
        for (int t = 0; t < 2; ++t)
#pragma unroll
            for (int i = 0; i < 4; ++i) {
                int idx = (et * 16 + kg * 4 + i) * 64 + (dh2 * 2 + t) * 16 + r;
                atomicAdd(&Mb[idx], accM[t][i]);
            }
    }
#undef LOADX
#undef LOADW
#undef WRITE
}

// ---------- final_qm: out = Q @ (M/8)  (round-9 proven; 1/8 folded at load) ----------
__global__ __launch_bounds__(256)
void final_qm(const unsigned short* __restrict__ Qb, const float* __restrict__ M8acc,
              float* __restrict__ out) {
    int blk = blockIdx.x;            // 0..255
    int b = blk >> 6;
    int s0 = (blk & 63) * 64;
    int tid = threadIdx.x;
    int wv = tid >> 6, lane = tid & 63;
    int r = lane & 15, kg = lane >> 4;

    __shared__ unsigned short Ml[4096];  // M/8 as bf16 [e][d]
#pragma unroll
    for (int j = 0; j < 16; ++j) {
        int i2 = j * 256 + tid;
        Ml[i2] = f2bf(M8acc[b * 4096 + i2] * 0.125f);
    }
    __syncthreads();

    const unsigned short* qrow = Qb + ((size_t)b * S_ + s0 + wv * 16 + r) * 64;
    f32x4 acc[4] = {};
#pragma unroll
    for (int ks2 = 0; ks2 < 2; ++ks2) {
        bf16x8 af = *(const bf16x8*)(qrow + ks2 * 32 + kg * 8);
#pragma unroll
        for (int nt = 0; nt < 4; ++nt) {
            bf16x8 bfm;
#pragma unroll
            for (int i = 0; i < 8; ++i)
                bfm[i] = (short)Ml[(ks2 * 32 + kg * 8 + i) * 64 + nt * 16 + r];
            acc[nt] = __builtin_amdgcn_mfma_f32_16x16x32_bf16(af, bfm, acc[nt], 0, 0, 0);
        }
    }
    float* orow = out + ((size_t)b * S_ + s0 + wv * 16) * 64;
#pragma unroll
    for (int nt = 0; nt < 4; ++nt)
#pragma unroll
        for (int i = 0; i < 4; ++i)
            orow[(kg * 4 + i) * 64 + nt * 16 + r] = acc[nt][i];
}

extern "C" void kernel_launch(void* const* d_in, const int* in_sizes, int n_in,
                              void* d_out, int out_size, void* d_ws, size_t ws_size,
                              hipStream_t stream) {
    const float* x  = (const float*)d_in[0];
    const float* Wk = (const float*)d_in[1];
    const float* Wq = (const float*)d_in[2];
    const float* Wv = (const float*)d_in[3];
    float* out = (float*)d_out;

    if (ws_size < 2555904) return;  // diagnostic guard

    char* ws = (char*)d_ws;
    // layout (total 2,555,904 B):
    // WT[384K bf16 x3] | M8acc[64K fp32] | Qb[2M bf16]
    unsigned short* WT  = (unsigned short*)(ws);
    float* M8acc        = (float*)(ws + 393216);
    unsigned short* Qb  = (unsigned short*)(ws + 458752);

    prep_w3z<<<768, 256, 0, stream>>>(Wk, Wv, Wq, WT, M8acc);
    kv_moment13<<<256, 768, 0, stream>>>(x, WT, M8acc, Qb);
    final_qm<<<256, 256, 0, stream>>>(Qb, M8acc, out);
}